// Round 1
// baseline (172.930 us; speedup 1.0000x reference)
//
#include <hip/hip_runtime.h>

#define NB 32768
#define NF 256
#define H1 16
#define HH 8            // H1 rows handled per thread (pair-split)
#define H2 8
#define R_PER_BLOCK 64
#define CHUNK 16
#define NT 512          // 2 threads per feature

__device__ __forceinline__ float elu_f(float v) {
    return v > 0.0f ? v : (__expf(v) - 1.0f);
}

__global__ __launch_bounds__(NT, 4)
void nul_kernel(const float* __restrict__ x,
                const float* __restrict__ W1, const float* __restrict__ b1,
                const float* __restrict__ W2, const float* __restrict__ b2,
                const float* __restrict__ W3, const float* __restrict__ b3,
                const float* __restrict__ theta, const float* __restrict__ bias,
                float* __restrict__ y_out, float* __restrict__ w_out,
                float* __restrict__ z_out) {
    const int tid  = threadIdx.x;
    const int f    = tid >> 1;           // feature
    const int half = tid & 1;            // which half of H1 this lane owns
    const int rowBase = blockIdx.x * R_PER_BLOCK;

    // ---- per-thread params -> registers (float4 loads) ----
    float w1v[HH], b1v[HH];
    {
        const float4* p = reinterpret_cast<const float4*>(W1 + f * H1 + half * HH);
        float4 v0 = p[0], v1 = p[1];
        w1v[0]=v0.x; w1v[1]=v0.y; w1v[2]=v0.z; w1v[3]=v0.w;
        w1v[4]=v1.x; w1v[5]=v1.y; w1v[6]=v1.z; w1v[7]=v1.w;
    }
    {
        const float4* p = reinterpret_cast<const float4*>(b1 + f * H1 + half * HH);
        float4 v0 = p[0], v1 = p[1];
        b1v[0]=v0.x; b1v[1]=v0.y; b1v[2]=v0.z; b1v[3]=v0.w;
        b1v[4]=v1.x; b1v[5]=v1.y; b1v[6]=v1.z; b1v[7]=v1.w;
    }
    float w2v[HH * H2];                  // my 8 rows of W2[f] (64 floats)
    {
        const float4* p = reinterpret_cast<const float4*>(W2 + f * H1 * H2 + half * HH * H2);
        #pragma unroll
        for (int i = 0; i < (HH * H2) / 4; ++i) {
            float4 v = p[i];
            w2v[4*i]=v.x; w2v[4*i+1]=v.y; w2v[4*i+2]=v.z; w2v[4*i+3]=v.w;
        }
    }
    float b2i[H2];                       // b2 on half==0, zeros on half==1
    {
        const float4* p = reinterpret_cast<const float4*>(b2 + f * H2);
        float4 v0 = p[0], v1 = p[1];
        const float m = (half == 0) ? 1.0f : 0.0f;
        b2i[0]=v0.x*m; b2i[1]=v0.y*m; b2i[2]=v0.z*m; b2i[3]=v0.w*m;
        b2i[4]=v1.x*m; b2i[5]=v1.y*m; b2i[6]=v1.z*m; b2i[7]=v1.w*m;
    }
    float w3v[H2];
    {
        const float4* p = reinterpret_cast<const float4*>(W3 + f * H2);
        float4 v0 = p[0], v1 = p[1];
        w3v[0]=v0.x; w3v[1]=v0.y; w3v[2]=v0.z; w3v[3]=v0.w;
        w3v[4]=v1.x; w3v[5]=v1.y; w3v[6]=v1.z; w3v[7]=v1.w;
    }
    const float b3v   = b3[f];
    const float th    = theta[f];
    const float wv    = logf(1.0f + __expf(th));   // softplus (same as verified kernel)
    const float biasv = bias[0];

    if (blockIdx.x == 0 && half == 0) w_out[f] = wv;

    __shared__ float P[CHUNK][NF + 1];   // +1 pad vs bank conflicts

    // rotating prefetch of x (pair lanes load the same address -> merged)
    float xnext = x[rowBase * NF + f];

    for (int c = 0; c < R_PER_BLOCK; c += CHUNK) {
        #pragma unroll 1
        for (int r = 0; r < CHUNK; ++r) {
            const int row = rowBase + c + r;
            const float xv = xnext;
            int nrow = row + 1; if (nrow >= NB) nrow = row;
            xnext = x[nrow * NF + f];    // prefetch next row

            // partial layer1+layer2 over my half of H1 (h1 consumed immediately)
            float acc[H2];
            #pragma unroll
            for (int k = 0; k < H2; ++k) acc[k] = b2i[k];
            #pragma unroll
            for (int h = 0; h < HH; ++h) {
                const float h1 = elu_f(fmaf(xv, w1v[h], b1v[h]));
                #pragma unroll
                for (int k = 0; k < H2; ++k)
                    acc[k] = fmaf(h1, w2v[h * H2 + k], acc[k]);
            }

            // combine the pair's partial sums (lane 2f <-> lane 2f+1)
            #pragma unroll
            for (int k = 0; k < H2; ++k)
                acc[k] += __shfl_xor(acc[k], 1, 64);

            // layer 3 (redundant in both lanes of the pair; static indexing)
            float z = b3v;
            #pragma unroll
            for (int k = 0; k < H2; ++k)
                z = fmaf(elu_f(acc[k]), w3v[k], z);

            if (half == 0) {
                z_out[row * NF + f] = z;   // even lanes -> contiguous addresses
                P[r][f] = wv * z;          // stage for y reduction
            }
        }
        __syncthreads();
        if (tid < 256) {
            // 16 rows x 256 partials, 16 threads per row
            const int rr = tid >> 4;
            const int l  = tid & 15;
            float s = 0.0f;
            #pragma unroll
            for (int i = 0; i < 16; ++i) s += P[rr][i * 16 + l];
            #pragma unroll
            for (int o = 8; o > 0; o >>= 1) s += __shfl_down(s, o, 16);
            if (l == 0) y_out[rowBase + c + rr] = s + biasv;
        }
        __syncthreads();
    }
}

extern "C" void kernel_launch(void* const* d_in, const int* in_sizes, int n_in,
                              void* d_out, int out_size, void* d_ws, size_t ws_size,
                              hipStream_t stream) {
    const float* x     = (const float*)d_in[0];
    const float* W1    = (const float*)d_in[1];
    const float* b1    = (const float*)d_in[2];
    const float* W2    = (const float*)d_in[3];
    const float* b2    = (const float*)d_in[4];
    const float* W3    = (const float*)d_in[5];
    const float* b3    = (const float*)d_in[6];
    const float* theta = (const float*)d_in[7];
    const float* bias  = (const float*)d_in[8];

    float* y_out = (float*)d_out;                  // [32768]
    float* w_out = y_out + NB;                     // [256]
    float* z_out = w_out + NF;                     // [32768*256]

    nul_kernel<<<NB / R_PER_BLOCK, NT, 0, stream>>>(
        x, W1, b1, W2, b2, W3, b3, theta, bias, y_out, w_out, z_out);
}